// Round 4
// baseline (3838.980 us; speedup 1.0000x reference)
//
#include <hip/hip_runtime.h>
#include <hip/hip_fp16.h>

#define NB 8
#define P 1024
#define D 64
#define EPSF 0.1f
#define INV_EPS 10.0f
#define MAX_IT 100
// eps * log(1/P + 1e-8), P=1024
#define EPS_LOG_MU (-0.693146162f)
#define IB 512              // iter_k blocks (64 per batch)
#define BPB 64              // blocks per batch

// ws layout in FLOATS
#define HALF_F (NB * P * P / 2)              // 4,194,304
#define OFF_Z    0                           // z  = -C/eps, row-major fp16
#define OFF_ZT   (HALF_F)                    // z^T (gemm with x<->y swapped)
#define OFF_U    (2 * HALF_F)
#define OFF_V    (OFF_U + NB * P)
#define OFF_X2   (OFF_V + NB * P)
#define OFF_Y2   (OFF_X2 + NB * P)
#define OFF_UH   (OFF_Y2 + NB * P)           // u history: MAX_IT * NB*P
#define OFF_DU   (OFF_UH + MAX_IT * NB * P)  // du partials: MAX_IT * IB
#define OFF_BAR  (OFF_DU + MAX_IT * IB)      // 256 uints (8 padded counters)
#define OFF_T    (OFF_BAR + 256)             // T as int
#define OFF_COST (OFF_T + 64)
#define WS_FLOATS (OFF_COST + 64)            // ~37.2 MB

// ---------------- init ----------------
__global__ __launch_bounds__(256)
void init_k(const float* __restrict__ x, const float* __restrict__ y,
            float* __restrict__ ws)
{
    const int g = blockIdx.x * 256 + threadIdx.x;
    if (g < NB * P) {
        const float4* xr = (const float4*)(x + (size_t)g * D);
        const float4* yr = (const float4*)(y + (size_t)g * D);
        float sx = 0.f, sy = 0.f;
#pragma unroll
        for (int k = 0; k < D / 4; k++) {
            float4 a = xr[k], b = yr[k];
            sx = fmaf(a.x, a.x, fmaf(a.y, a.y, fmaf(a.z, a.z, fmaf(a.w, a.w, sx))));
            sy = fmaf(b.x, b.x, fmaf(b.y, b.y, fmaf(b.z, b.z, fmaf(b.w, b.w, sy))));
        }
        ws[OFF_X2 + g] = sx; ws[OFF_Y2 + g] = sy;
        ws[OFF_U + g] = 0.f; ws[OFF_V + g] = 0.f;
    }
    if (g < 256) ((unsigned*)(ws + OFF_BAR))[g] = 0u;
    if (g < 64)  ws[OFF_COST + g] = 0.f;
}

// ---------------- z and z^T via LDS GEMM, fp16 out ----------------
// grid 1024: blocks 0..511 -> z (rows=x), 512..1023 -> z^T (rows=y).
// ysT uses an XOR granule swizzle: (d, col) stored at
//   d*64 + (((col>>2) ^ ((d>>2)&15)) << 2) + (col&3)
// -> both the staging writes and the b128 reads are conflict-free (2-way).
__global__ __launch_bounds__(256)
void gemm_k(const float* __restrict__ x, const float* __restrict__ y,
            float* __restrict__ ws)
{
    float* x2 = ws + OFF_X2;
    float* y2 = ws + OFF_Y2;
    const int tid   = threadIdx.x;
    const int half_ = blockIdx.x >> 9;
    const int bid   = blockIdx.x & 511;
    const int nB    = bid & 7;
    const int inner = bid >> 3;

    const float* A  = half_ ? y : x;
    const float* B  = half_ ? x : y;
    const float* ra = (half_ ? y2 : x2) + nB * P;
    const float* rb = (half_ ? x2 : y2) + nB * P;
    __half* out = (__half*)(ws + (half_ ? OFF_ZT : OFF_Z)) + (size_t)nB * P * P;

    __shared__ float xs [64 * 68];
    __shared__ float ysT[64 * 64];

    for (int k4 = 0; k4 < 4; k4++) {
        const int t  = inner * 4 + k4;
        const int ti = t >> 4, tj = t & 15;
        const float* abase = A + (size_t)(nB * P + ti * 64) * D;
        const float* bbase = B + (size_t)(nB * P + tj * 64) * D;
#pragma unroll
        for (int k = 0; k < 4; k++) {
            const int f = k * 1024 + tid * 4;
            const int r = f >> 6, c = f & 63;     // r: tile row (out col), c: d-index
            float4 a = *(const float4*)(abase + f);
            *(float4*)(xs + r * 68 + c) = a;
            float4 b = *(const float4*)(bbase + f);
            const int pr  = r >> 2;               // col granule
            const int r3  = r & 3;
            const int t15 = c >> 2;               // d granule (same for c..c+3)
            ysT[(c + 0) * 64 + (((pr ^ t15) & 15) << 2) + r3] = b.x;
            ysT[(c + 1) * 64 + (((pr ^ t15) & 15) << 2) + r3] = b.y;
            ysT[(c + 2) * 64 + (((pr ^ t15) & 15) << 2) + r3] = b.z;
            ysT[(c + 3) * 64 + (((pr ^ t15) & 15) << 2) + r3] = b.w;
        }
        __syncthreads();
        const int r0 = tid >> 4;
        const int g  = tid & 15;                  // col granule this thread owns
        const int c0 = g << 2;
#pragma unroll
        for (int rr = 0; rr < 4; rr++) {
            const int row = rr * 16 + r0;
            const float* xrow = xs + row * 68;
            float s0 = 0.f, s1 = 0.f, s2 = 0.f, s3 = 0.f;
#pragma unroll
            for (int d = 0; d < 64; d++) {
                const float xv = xrow[d];
                const float4 yv = *(const float4*)(ysT + d * 64 + ((g ^ ((d >> 2) & 15)) << 2));
                s0 = fmaf(xv, yv.x, s0); s1 = fmaf(xv, yv.y, s1);
                s2 = fmaf(xv, yv.z, s2); s3 = fmaf(xv, yv.w, s3);
            }
            const int gr = ti * 64 + row;
            const int gc = tj * 64 + c0;
            const float xq = ra[gr];
            union { unsigned long long u64; __half h[4]; } p;
            p.h[0] = __float2half_rn(-fmaxf(xq + rb[gc + 0] - 2.f * s0, 0.f) * INV_EPS);
            p.h[1] = __float2half_rn(-fmaxf(xq + rb[gc + 1] - 2.f * s1, 0.f) * INV_EPS);
            p.h[2] = __float2half_rn(-fmaxf(xq + rb[gc + 2] - 2.f * s2, 0.f) * INV_EPS);
            p.h[3] = __float2half_rn(-fmaxf(xq + rb[gc + 3] - 2.f * s3, 0.f) * INV_EPS);
            *(unsigned long long*)(out + (size_t)gr * P + gc) = p.u64;
        }
        __syncthreads();
    }
}

// unpack 8 halfs (one float4) + 8 weights -> z[8]
__device__ __forceinline__ void unpack8(float4 cv, float4 wa, float4 wb, float* zp)
{
    const __half2* h = (const __half2*)&cv;
    float2 f;
    f = __half22float2(h[0]); zp[0] = fmaf(wa.x, INV_EPS, f.x); zp[1] = fmaf(wa.y, INV_EPS, f.y);
    f = __half22float2(h[1]); zp[2] = fmaf(wa.z, INV_EPS, f.x); zp[3] = fmaf(wa.w, INV_EPS, f.y);
    f = __half22float2(h[2]); zp[4] = fmaf(wb.x, INV_EPS, f.x); zp[5] = fmaf(wb.y, INV_EPS, f.y);
    f = __half22float2(h[3]); zp[6] = fmaf(wb.z, INV_EPS, f.x); zp[7] = fmaf(wb.w, INV_EPS, f.y);
}

// LSE over one matrix row (1024 fp16) + weight vector; result on all lanes.
__device__ __forceinline__ float lse_row(const __half* mat, const float4* wv,
                                         int row, int lane)
{
    const float4* mr = (const float4*)(mat + (size_t)row * P);
    const float4 ca = mr[lane];
    const float4 cb = mr[lane + 64];
    const float4 wa0 = wv[2 * lane],       wa1 = wv[2 * lane + 1];
    const float4 wb0 = wv[128 + 2 * lane], wb1 = wv[129 + 2 * lane];
    float z[16];
    unpack8(ca, wa0, wa1, z);
    unpack8(cb, wb0, wb1, z + 8);
    float m = -1e30f;
#pragma unroll
    for (int q = 0; q < 16; q++) m = fmaxf(m, z[q]);
#pragma unroll
    for (int off = 32; off; off >>= 1) m = fmaxf(m, __shfl_xor(m, off, 64));
    float s = 0.f;
#pragma unroll
    for (int q = 0; q < 16; q++) s += __expf(z[q] - m);
#pragma unroll
    for (int off = 32; off; off >>= 1) s += __shfl_xor(s, off, 64);
    return EPS_LOG_MU - EPSF * (m + __logf(s));
}

// per-batch barrier: monotonic arrival counter + agent-scope fences (G16)
__device__ __forceinline__ void batch_barrier(unsigned* bar, unsigned target)
{
    __syncthreads();
    if (threadIdx.x == 0) {
        __builtin_amdgcn_fence(__ATOMIC_RELEASE, "agent");
        __hip_atomic_fetch_add(bar, 1u, __ATOMIC_RELAXED, __HIP_MEMORY_SCOPE_AGENT);
        int guard = 0;
        while (__hip_atomic_load(bar, __ATOMIC_RELAXED, __HIP_MEMORY_SCOPE_AGENT) < target) {
            __builtin_amdgcn_s_sleep(2);
            if (++guard > (1 << 16)) break;   // degrade, never hang
        }
        __builtin_amdgcn_fence(__ATOMIC_ACQUIRE, "agent");
    }
    __syncthreads();
}

// ---------------- persistent iteration kernel ----------------
__global__ __launch_bounds__(256)
void iter_k(float* __restrict__ ws)
{
    const __half* z  = (const __half*)(ws + OFF_Z);
    const __half* zT = (const __half*)(ws + OFF_ZT);
    float* u  = ws + OFF_U;
    float* v  = ws + OFF_V;
    float* uh = ws + OFF_UH;
    float* dup = ws + OFF_DU;
    unsigned* bar = (unsigned*)(ws + OFF_BAR);

    const int tid   = threadIdx.x;
    const int nB    = blockIdx.x & 7;      // XCD pin
    const int inner = blockIdx.x >> 3;     // 0..63
    const int wid   = tid >> 6;
    const int lane  = tid & 63;
    __shared__ float duRed[4];

    const __half* zb  = z  + (size_t)nB * P * P;
    const __half* zTb = zT + (size_t)nB * P * P;
    const float4* vr = (const float4*)(v + nB * P);
    const float4* ur = (const float4*)(u + nB * P);
    unsigned* mybar = bar + nB * 32;       // 128B-padded counters

    float uold[4] = {0.f, 0.f, 0.f, 0.f};
    unsigned bstep = 0;

    for (int t = 0; t < MAX_IT; t++) {
        // ---- row pass: u
        float duw = 0.f;
#pragma unroll
        for (int rr = 0; rr < 4; rr++) {
            const int row = inner * 16 + wid * 4 + rr;
            const float un = lse_row(zb, vr, row, lane);
            if (lane == 0) {
                duw += fabsf(un - uold[rr]);
                uold[rr] = un;
                u[nB * P + row] = un;
                uh[(size_t)t * (NB * P) + nB * P + row] = un;
            }
        }
        if (lane == 0) duRed[wid] = duw;
        __syncthreads();
        if (tid == 0)
            dup[t * IB + blockIdx.x] = duRed[0] + duRed[1] + duRed[2] + duRed[3];
        batch_barrier(mybar, BPB * (++bstep));

        // ---- col pass: v
#pragma unroll
        for (int rr = 0; rr < 4; rr++) {
            const int col = inner * 16 + wid * 4 + rr;
            const float vn = lse_row(zTb, ur, col, lane);
            if (lane == 0) v[nB * P + col] = vn;
        }
        batch_barrier(mybar, BPB * (++bstep));
    }
}

// ---------------- find T, restore u_T ----------------
__global__ __launch_bounds__(1024)
void findT_k(float* __restrict__ ws)
{
    __shared__ float Spart[1024];
    __shared__ float S[MAX_IT];
    __shared__ int Ts;
    const int tid = threadIdx.x;

    // parallel partial sums: t = tid>>3 (0..127), sub = tid&7 sums 64 elems
    {
        const int t = tid >> 3, sub = tid & 7;
        float s = 0.f;
        if (t < MAX_IT) {
            const float* dp = ws + OFF_DU + t * IB + sub * 64;
            for (int i = 0; i < 64; i++) s += dp[i];
        }
        Spart[tid] = s;
    }
    __syncthreads();
    if (tid < MAX_IT) {
        float s = 0.f;
#pragma unroll
        for (int k = 0; k < 8; k++) s += Spart[tid * 8 + k];   // fixed order
        S[tid] = s;
    }
    __syncthreads();
    if (tid == 0) {
        int T = MAX_IT - 1;
        for (int t = 0; t < MAX_IT; t++) if (S[t] < 0.8f) { T = t; break; }
        Ts = T;
        *(int*)(ws + OFF_T) = T;
    }
    __syncthreads();
    const int T = Ts;
    const float* src = ws + OFF_UH + (size_t)T * (NB * P);
    float* u = ws + OFF_U;
    for (int i = tid; i < NB * P; i += 1024) u[i] = src[i];
    if (tid < 64) ws[OFF_COST + tid] = 0.f;
}

// ---------------- recompute v_T = F(u_T) ----------------
__global__ __launch_bounds__(256)
void colT_k(float* __restrict__ ws)
{
    const __half* zT = (const __half*)(ws + OFF_ZT);
    float* u = ws + OFF_U;
    float* v = ws + OFF_V;
    const int tid   = threadIdx.x;
    const int nB    = blockIdx.x & 7;
    const int inner = blockIdx.x >> 3;
    const int wid   = tid >> 6;
    const int lane  = tid & 63;
    const __half* zTb = zT + (size_t)nB * P * P;
    const float4* ur = (const float4*)(u + nB * P);
#pragma unroll
    for (int rr = 0; rr < 4; rr++) {
        const int col = inner * 16 + wid * 4 + rr;
        const float vn = lse_row(zTb, ur, col, lane);
        if (lane == 0) v[nB * P + col] = vn;
    }
}

// ---------------- final cost ----------------
__global__ __launch_bounds__(256)
void cost_k(float* __restrict__ ws)
{
    const __half* z = (const __half*)(ws + OFF_Z);
    float* u    = ws + OFF_U;
    float* v    = ws + OFF_V;
    float* cost = ws + OFF_COST;
    const int tid   = threadIdx.x;
    const int nB    = blockIdx.x & 7;
    const int inner = blockIdx.x >> 3;
    const int wid   = tid >> 6;
    const int lane  = tid & 63;
    __shared__ float red[4];

    const float4* vr = (const float4*)(v + nB * P);
    float accW = 0.f;
#pragma unroll
    for (int rr = 0; rr < 4; rr++) {
        const int row = inner * 16 + wid * 4 + rr;
        const float4* mr = (const float4*)(z + ((size_t)nB * P + row) * P);
        const float4 ca = mr[lane];
        const float4 cb = mr[lane + 64];
        const float4 va0 = vr[2 * lane],       va1 = vr[2 * lane + 1];
        const float4 vb0 = vr[128 + 2 * lane], vb1 = vr[129 + 2 * lane];
        float zw[16];
        unpack8(ca, va0, va1, zw);
        unpack8(cb, vb0, vb1, zw + 8);
        float zc[16];
        {
            const __half2* ha = (const __half2*)&ca;
            const __half2* hb = (const __half2*)&cb;
            float2 f;
            f = __half22float2(ha[0]); zc[0] = f.x;  zc[1] = f.y;
            f = __half22float2(ha[1]); zc[2] = f.x;  zc[3] = f.y;
            f = __half22float2(ha[2]); zc[4] = f.x;  zc[5] = f.y;
            f = __half22float2(ha[3]); zc[6] = f.x;  zc[7] = f.y;
            f = __half22float2(hb[0]); zc[8] = f.x;  zc[9] = f.y;
            f = __half22float2(hb[1]); zc[10] = f.x; zc[11] = f.y;
            f = __half22float2(hb[2]); zc[12] = f.x; zc[13] = f.y;
            f = __half22float2(hb[3]); zc[14] = f.x; zc[15] = f.y;
        }
        const float ui = u[nB * P + row] * INV_EPS;
#pragma unroll
        for (int q = 0; q < 16; q++)
            accW += __expf(zw[q] + ui) * zc[q];
    }
#pragma unroll
    for (int off = 32; off; off >>= 1) accW += __shfl_xor(accW, off, 64);
    if (lane == 0) red[wid] = accW;
    __syncthreads();
    if (tid == 0)
        atomicAdd(&cost[nB], -EPSF * (red[0] + red[1] + red[2] + red[3]));
}

__global__ void out_k(const float* __restrict__ ws, float* __restrict__ out)
{
    if (threadIdx.x < NB) out[threadIdx.x] = ws[OFF_COST + threadIdx.x];
}

__global__ void sentinel_k(float* __restrict__ out)
{
    if (threadIdx.x < NB) out[threadIdx.x] = 1.0e6f;
}

extern "C" void kernel_launch(void* const* d_in, const int* in_sizes, int n_in,
                              void* d_out, int out_size, void* d_ws, size_t ws_size,
                              hipStream_t stream) {
    const float* x = (const float*)d_in[0];
    const float* y = (const float*)d_in[1];
    float* ws  = (float*)d_ws;
    float* out = (float*)d_out;

    if (ws_size < (size_t)WS_FLOATS * sizeof(float)) {
        sentinel_k<<<1, 64, 0, stream>>>(out);
        return;
    }

    init_k<<<32, 256, 0, stream>>>(x, y, ws);
    gemm_k<<<1024, 256, 0, stream>>>(x, y, ws);
    iter_k<<<IB, 256, 0, stream>>>(ws);
    findT_k<<<1, 1024, 0, stream>>>(ws);
    colT_k<<<512, 256, 0, stream>>>(ws);
    cost_k<<<512, 256, 0, stream>>>(ws);
    out_k<<<1, 64, 0, stream>>>(ws, out);
}

// Round 5
// 1807.817 us; speedup vs baseline: 2.1235x; 2.1235x over previous
//
#include <hip/hip_runtime.h>
#include <hip/hip_fp16.h>

#define NB 8
#define P 1024
#define D 64
#define EPSF 0.1f
#define INV_EPS 10.0f
#define MAX_IT 100
// eps * log(1/P + 1e-8), P=1024
#define EPS_LOG_MU (-0.693146162f)
#define IB 512              // iter_k blocks (64 per batch)
#define BPB 64              // blocks per batch

// ws layout in FLOATS
#define HALF_F (NB * P * P / 2)              // 4,194,304
#define OFF_Z    0                           // z  = -C/eps, row-major fp16
#define OFF_ZT   (HALF_F)                    // z^T (gemm with x<->y swapped)
#define OFF_U    (2 * HALF_F)
#define OFF_V    (OFF_U + NB * P)
#define OFF_X2   (OFF_V + NB * P)
#define OFF_Y2   (OFF_X2 + NB * P)
#define OFF_UH   (OFF_Y2 + NB * P)           // u history: MAX_IT * NB*P
#define OFF_DU   (OFF_UH + MAX_IT * NB * P)  // du partials: MAX_IT * IB
#define OFF_BAR  (OFF_DU + MAX_IT * IB)      // 256 uints (8 padded counters)
#define OFF_T    (OFF_BAR + 256)             // T as int
#define OFF_COST (OFF_T + 64)
#define WS_FLOATS (OFF_COST + 64)            // ~37.2 MB (proven available)

// system-scope (sc0|sc1) publish/read: crosses XCD L2s, NO cache maintenance
__device__ __forceinline__ void publish_f(float* p, float v) {
    __hip_atomic_store(p, v, __ATOMIC_RELAXED, __HIP_MEMORY_SCOPE_SYSTEM);
}
__device__ __forceinline__ float readsys_f(const float* p) {
    return __hip_atomic_load(p, __ATOMIC_RELAXED, __HIP_MEMORY_SCOPE_SYSTEM);
}

// ---------------- init ----------------
__global__ __launch_bounds__(256)
void init_k(const float* __restrict__ x, const float* __restrict__ y,
            float* __restrict__ ws)
{
    const int g = blockIdx.x * 256 + threadIdx.x;
    if (g < NB * P) {
        const float4* xr = (const float4*)(x + (size_t)g * D);
        const float4* yr = (const float4*)(y + (size_t)g * D);
        float sx = 0.f, sy = 0.f;
#pragma unroll
        for (int k = 0; k < D / 4; k++) {
            float4 a = xr[k], b = yr[k];
            sx = fmaf(a.x, a.x, fmaf(a.y, a.y, fmaf(a.z, a.z, fmaf(a.w, a.w, sx))));
            sy = fmaf(b.x, b.x, fmaf(b.y, b.y, fmaf(b.z, b.z, fmaf(b.w, b.w, sy))));
        }
        ws[OFF_X2 + g] = sx; ws[OFF_Y2 + g] = sy;
        ws[OFF_U + g] = 0.f; ws[OFF_V + g] = 0.f;
    }
    if (g < 256) ((unsigned*)(ws + OFF_BAR))[g] = 0u;
    if (g < 64)  ws[OFF_COST + g] = 0.f;
}

// ---------------- z and z^T via LDS GEMM, fp16 out ----------------
__global__ __launch_bounds__(256)
void gemm_k(const float* __restrict__ x, const float* __restrict__ y,
            float* __restrict__ ws)
{
    float* x2 = ws + OFF_X2;
    float* y2 = ws + OFF_Y2;
    const int tid   = threadIdx.x;
    const int half_ = blockIdx.x >> 9;
    const int bid   = blockIdx.x & 511;
    const int nB    = bid & 7;
    const int inner = bid >> 3;

    const float* A  = half_ ? y : x;
    const float* B  = half_ ? x : y;
    const float* ra = (half_ ? y2 : x2) + nB * P;
    const float* rb = (half_ ? x2 : y2) + nB * P;
    __half* out = (__half*)(ws + (half_ ? OFF_ZT : OFF_Z)) + (size_t)nB * P * P;

    __shared__ float xs [64 * 68];
    __shared__ float ysT[64 * 64];

    for (int k4 = 0; k4 < 4; k4++) {
        const int t  = inner * 4 + k4;
        const int ti = t >> 4, tj = t & 15;
        const float* abase = A + (size_t)(nB * P + ti * 64) * D;
        const float* bbase = B + (size_t)(nB * P + tj * 64) * D;
#pragma unroll
        for (int k = 0; k < 4; k++) {
            const int f = k * 1024 + tid * 4;
            const int r = f >> 6, c = f & 63;
            float4 a = *(const float4*)(abase + f);
            *(float4*)(xs + r * 68 + c) = a;
            float4 b = *(const float4*)(bbase + f);
            const int pr  = r >> 2;
            const int r3  = r & 3;
            const int t15 = c >> 2;
            ysT[(c + 0) * 64 + (((pr ^ t15) & 15) << 2) + r3] = b.x;
            ysT[(c + 1) * 64 + (((pr ^ t15) & 15) << 2) + r3] = b.y;
            ysT[(c + 2) * 64 + (((pr ^ t15) & 15) << 2) + r3] = b.z;
            ysT[(c + 3) * 64 + (((pr ^ t15) & 15) << 2) + r3] = b.w;
        }
        __syncthreads();
        const int r0 = tid >> 4;
        const int g  = tid & 15;
        const int c0 = g << 2;
#pragma unroll
        for (int rr = 0; rr < 4; rr++) {
            const int row = rr * 16 + r0;
            const float* xrow = xs + row * 68;
            float s0 = 0.f, s1 = 0.f, s2 = 0.f, s3 = 0.f;
#pragma unroll
            for (int d = 0; d < 64; d++) {
                const float xv = xrow[d];
                const float4 yv = *(const float4*)(ysT + d * 64 + ((g ^ ((d >> 2) & 15)) << 2));
                s0 = fmaf(xv, yv.x, s0); s1 = fmaf(xv, yv.y, s1);
                s2 = fmaf(xv, yv.z, s2); s3 = fmaf(xv, yv.w, s3);
            }
            const int gr = ti * 64 + row;
            const int gc = tj * 64 + c0;
            const float xq = ra[gr];
            union { unsigned long long u64; __half h[4]; } p;
            p.h[0] = __float2half_rn(-fmaxf(xq + rb[gc + 0] - 2.f * s0, 0.f) * INV_EPS);
            p.h[1] = __float2half_rn(-fmaxf(xq + rb[gc + 1] - 2.f * s1, 0.f) * INV_EPS);
            p.h[2] = __float2half_rn(-fmaxf(xq + rb[gc + 2] - 2.f * s2, 0.f) * INV_EPS);
            p.h[3] = __float2half_rn(-fmaxf(xq + rb[gc + 3] - 2.f * s3, 0.f) * INV_EPS);
            *(unsigned long long*)(out + (size_t)gr * P + gc) = p.u64;
        }
        __syncthreads();
    }
}

// unpack 8 halfs (one float4) + 8 weights -> z[8]
__device__ __forceinline__ void unpack8(float4 cv, float4 wa, float4 wb, float* zp)
{
    const __half2* h = (const __half2*)&cv;
    float2 f;
    f = __half22float2(h[0]); zp[0] = fmaf(wa.x, INV_EPS, f.x); zp[1] = fmaf(wa.y, INV_EPS, f.y);
    f = __half22float2(h[1]); zp[2] = fmaf(wa.z, INV_EPS, f.x); zp[3] = fmaf(wa.w, INV_EPS, f.y);
    f = __half22float2(h[2]); zp[4] = fmaf(wb.x, INV_EPS, f.x); zp[5] = fmaf(wb.y, INV_EPS, f.y);
    f = __half22float2(h[3]); zp[6] = fmaf(wb.z, INV_EPS, f.x); zp[7] = fmaf(wb.w, INV_EPS, f.y);
}

// LSE over one matrix row (1024 fp16), weights from an array (global or LDS)
template <typename WPtr>
__device__ __forceinline__ float lse_row(const __half* mat, WPtr wv,
                                         int row, int lane)
{
    const float4* mr = (const float4*)(mat + (size_t)row * P);
    const float4 ca = mr[lane];
    const float4 cb = mr[lane + 64];
    const float4 wa0 = wv[2 * lane],       wa1 = wv[2 * lane + 1];
    const float4 wb0 = wv[128 + 2 * lane], wb1 = wv[129 + 2 * lane];
    float z[16];
    unpack8(ca, wa0, wa1, z);
    unpack8(cb, wb0, wb1, z + 8);
    float m = -1e30f;
#pragma unroll
    for (int q = 0; q < 16; q++) m = fmaxf(m, z[q]);
#pragma unroll
    for (int off = 32; off; off >>= 1) m = fmaxf(m, __shfl_xor(m, off, 64));
    float s = 0.f;
#pragma unroll
    for (int q = 0; q < 16; q++) s += __expf(z[q] - m);
#pragma unroll
    for (int off = 32; off; off >>= 1) s += __shfl_xor(s, off, 64);
    return EPS_LOG_MU - EPSF * (m + __logf(s));
}

// per-batch barrier: plain atomic counter + system-scope poll. NO fences,
// NO L2 writeback/invalidate. Correct for any block->XCD placement (m20:
// default atomics are device-coherent; system-scope loads read the fabric).
__device__ __forceinline__ void bbar(unsigned* ctr, unsigned target)
{
    __syncthreads();                        // per-wave vmcnt(0) before s_barrier
    if (threadIdx.x == 0) {
        __builtin_amdgcn_s_waitcnt(0);      // belt & suspenders: drain own stores
        __hip_atomic_fetch_add(ctr, 1u, __ATOMIC_RELAXED, __HIP_MEMORY_SCOPE_AGENT);
        unsigned g = 0;
        while (__hip_atomic_load(ctr, __ATOMIC_RELAXED, __HIP_MEMORY_SCOPE_SYSTEM) < target) {
            __builtin_amdgcn_s_sleep(2);
            if (++g > (1u << 15)) break;    // degrade (visibly wrong), never hang
        }
    }
    __syncthreads();
}

// ---------------- persistent iteration kernel ----------------
__global__ __launch_bounds__(256, 2)
void iter_k(float* __restrict__ ws)
{
    const __half* z  = (const __half*)(ws + OFF_Z);
    const __half* zT = (const __half*)(ws + OFF_ZT);
    float* u   = ws + OFF_U;
    float* v   = ws + OFF_V;
    float* uh  = ws + OFF_UH;
    float* dup = ws + OFF_DU;

    const int tid   = threadIdx.x;
    const int nB    = blockIdx.x & 7;
    const int inner = blockIdx.x >> 3;
    const int wid   = tid >> 6;
    const int lane  = tid & 63;

    __shared__ float wstage[P];      // staged weight vector (4 KB)
    __shared__ float duRed[4];

    const __half* zb  = z  + (size_t)nB * P * P;
    const __half* zTb = zT + (size_t)nB * P * P;
    unsigned* ctr = (unsigned*)(ws + OFF_BAR) + nB * 32;   // 128B-padded

    float uold[4] = {0.f, 0.f, 0.f, 0.f};
    unsigned bstep = 0;

    for (int t = 0; t < MAX_IT; t++) {
        // ---- stage v into LDS (system-scope reads: always fresh)
        {
            const float* vsrc = v + nB * P + tid * 4;
            float4 w;
            w.x = readsys_f(vsrc + 0); w.y = readsys_f(vsrc + 1);
            w.z = readsys_f(vsrc + 2); w.w = readsys_f(vsrc + 3);
            *(float4*)(wstage + tid * 4) = w;
        }
        __syncthreads();

        // ---- row pass: u
        float duw = 0.f;
#pragma unroll
        for (int rr = 0; rr < 4; rr++) {
            const int row = inner * 16 + wid * 4 + rr;
            const float un = lse_row(zb, (const float4*)wstage, row, lane);
            if (lane == 0) {
                duw += fabsf(un - uold[rr]);
                uold[rr] = un;
                publish_f(&u[nB * P + row], un);
                uh[(size_t)t * (NB * P) + nB * P + row] = un;
            }
        }
        if (lane == 0) duRed[wid] = duw;
        __syncthreads();
        if (tid == 0)
            dup[t * IB + blockIdx.x] = duRed[0] + duRed[1] + duRed[2] + duRed[3];
        bbar(ctr, BPB * (++bstep));

        // ---- stage u into LDS
        {
            const float* usrc = u + nB * P + tid * 4;
            float4 w;
            w.x = readsys_f(usrc + 0); w.y = readsys_f(usrc + 1);
            w.z = readsys_f(usrc + 2); w.w = readsys_f(usrc + 3);
            *(float4*)(wstage + tid * 4) = w;
        }
        __syncthreads();

        // ---- col pass: v
#pragma unroll
        for (int rr = 0; rr < 4; rr++) {
            const int col = inner * 16 + wid * 4 + rr;
            const float vn = lse_row(zTb, (const float4*)wstage, col, lane);
            if (lane == 0) publish_f(&v[nB * P + col], vn);
        }
        bbar(ctr, BPB * (++bstep));
    }
}

// ---------------- find T, restore u_T ----------------
__global__ __launch_bounds__(1024)
void findT_k(float* __restrict__ ws)
{
    __shared__ float Spart[1024];
    __shared__ float S[MAX_IT];
    __shared__ int Ts;
    const int tid = threadIdx.x;

    {
        const int t = tid >> 3, sub = tid & 7;
        float s = 0.f;
        if (t < MAX_IT) {
            const float* dp = ws + OFF_DU + t * IB + sub * 64;
            for (int i = 0; i < 64; i++) s += dp[i];
        }
        Spart[tid] = s;
    }
    __syncthreads();
    if (tid < MAX_IT) {
        float s = 0.f;
#pragma unroll
        for (int k = 0; k < 8; k++) s += Spart[tid * 8 + k];
        S[tid] = s;
    }
    __syncthreads();
    if (tid == 0) {
        int T = MAX_IT - 1;
        for (int t = 0; t < MAX_IT; t++) if (S[t] < 0.8f) { T = t; break; }
        Ts = T;
        *(int*)(ws + OFF_T) = T;
    }
    __syncthreads();
    const int T = Ts;
    const float* src = ws + OFF_UH + (size_t)T * (NB * P);
    float* u = ws + OFF_U;
    for (int i = tid; i < NB * P; i += 1024) u[i] = src[i];
    if (tid < 64) ws[OFF_COST + tid] = 0.f;
}

// ---------------- recompute v_T = F(u_T) ----------------
__global__ __launch_bounds__(256)
void colT_k(float* __restrict__ ws)
{
    const __half* zT = (const __half*)(ws + OFF_ZT);
    float* u = ws + OFF_U;
    float* v = ws + OFF_V;
    const int tid   = threadIdx.x;
    const int nB    = blockIdx.x & 7;
    const int inner = blockIdx.x >> 3;
    const int wid   = tid >> 6;
    const int lane  = tid & 63;
    const __half* zTb = zT + (size_t)nB * P * P;
    const float4* ur = (const float4*)(u + nB * P);
#pragma unroll
    for (int rr = 0; rr < 4; rr++) {
        const int col = inner * 16 + wid * 4 + rr;
        const float vn = lse_row(zTb, ur, col, lane);
        if (lane == 0) v[nB * P + col] = vn;
    }
}

// ---------------- final cost ----------------
__global__ __launch_bounds__(256)
void cost_k(float* __restrict__ ws)
{
    const __half* z = (const __half*)(ws + OFF_Z);
    float* u    = ws + OFF_U;
    float* v    = ws + OFF_V;
    float* cost = ws + OFF_COST;
    const int tid   = threadIdx.x;
    const int nB    = blockIdx.x & 7;
    const int inner = blockIdx.x >> 3;
    const int wid   = tid >> 6;
    const int lane  = tid & 63;
    __shared__ float red[4];

    const float4* vr = (const float4*)(v + nB * P);
    float accW = 0.f;
#pragma unroll
    for (int rr = 0; rr < 4; rr++) {
        const int row = inner * 16 + wid * 4 + rr;
        const float4* mr = (const float4*)(z + ((size_t)nB * P + row) * P);
        const float4 ca = mr[lane];
        const float4 cb = mr[lane + 64];
        const float4 va0 = vr[2 * lane],       va1 = vr[2 * lane + 1];
        const float4 vb0 = vr[128 + 2 * lane], vb1 = vr[129 + 2 * lane];
        float zw[16];
        unpack8(ca, va0, va1, zw);
        unpack8(cb, vb0, vb1, zw + 8);
        float zc[16];
        {
            const __half2* ha = (const __half2*)&ca;
            const __half2* hb = (const __half2*)&cb;
            float2 f;
            f = __half22float2(ha[0]); zc[0] = f.x;  zc[1] = f.y;
            f = __half22float2(ha[1]); zc[2] = f.x;  zc[3] = f.y;
            f = __half22float2(ha[2]); zc[4] = f.x;  zc[5] = f.y;
            f = __half22float2(ha[3]); zc[6] = f.x;  zc[7] = f.y;
            f = __half22float2(hb[0]); zc[8] = f.x;  zc[9] = f.y;
            f = __half22float2(hb[1]); zc[10] = f.x; zc[11] = f.y;
            f = __half22float2(hb[2]); zc[12] = f.x; zc[13] = f.y;
            f = __half22float2(hb[3]); zc[14] = f.x; zc[15] = f.y;
        }
        const float ui = u[nB * P + row] * INV_EPS;
#pragma unroll
        for (int q = 0; q < 16; q++)
            accW += __expf(zw[q] + ui) * zc[q];
    }
#pragma unroll
    for (int off = 32; off; off >>= 1) accW += __shfl_xor(accW, off, 64);
    if (lane == 0) red[wid] = accW;
    __syncthreads();
    if (tid == 0)
        atomicAdd(&cost[nB], -EPSF * (red[0] + red[1] + red[2] + red[3]));
}

__global__ void out_k(const float* __restrict__ ws, float* __restrict__ out)
{
    if (threadIdx.x < NB) out[threadIdx.x] = ws[OFF_COST + threadIdx.x];
}

__global__ void sentinel_k(float* __restrict__ out)
{
    if (threadIdx.x < NB) out[threadIdx.x] = 1.0e6f;
}

extern "C" void kernel_launch(void* const* d_in, const int* in_sizes, int n_in,
                              void* d_out, int out_size, void* d_ws, size_t ws_size,
                              hipStream_t stream) {
    const float* x = (const float*)d_in[0];
    const float* y = (const float*)d_in[1];
    float* ws  = (float*)d_ws;
    float* out = (float*)d_out;

    if (ws_size < (size_t)WS_FLOATS * sizeof(float)) {
        sentinel_k<<<1, 64, 0, stream>>>(out);
        return;
    }

    init_k<<<32, 256, 0, stream>>>(x, y, ws);
    gemm_k<<<1024, 256, 0, stream>>>(x, y, ws);
    iter_k<<<IB, 256, 0, stream>>>(ws);
    findT_k<<<1, 1024, 0, stream>>>(ws);
    colT_k<<<512, 256, 0, stream>>>(ws);
    cost_k<<<512, 256, 0, stream>>>(ws);
    out_k<<<1, 64, 0, stream>>>(ws, out);
}

// Round 6
// 1144.434 us; speedup vs baseline: 3.3545x; 1.5797x over previous
//
#include <hip/hip_runtime.h>
#include <hip/hip_fp16.h>

#define NB 8
#define P 1024
#define D 64
#define EPSF 0.1f
#define INV_EPS 10.0f
#define MAX_IT 100
// eps * log(1/P + 1e-8), P=1024
#define EPS_LOG_MU (-0.693146162f)
#define IB 512              // iter_k blocks (64 per batch)
#define TPB_I 512           // threads per iter block (8 waves, 2 rows each)
#define BPB 64              // blocks per batch

// ws layout in FLOATS (identical footprint to R4 -- proven available)
#define HALF_F (NB * P * P / 2)              // 4,194,304
#define OFF_Z    0                           // z  = -C/eps, row-major fp16
#define OFF_ZT   (HALF_F)                    // z^T (gemm with x<->y swapped)
#define OFF_U    (2 * HALF_F)
#define OFF_V    (OFF_U + NB * P)
#define OFF_X2   (OFF_V + NB * P)
#define OFF_Y2   (OFF_X2 + NB * P)
#define OFF_UH   (OFF_Y2 + NB * P)           // u history: MAX_IT * NB*P
#define OFF_DU   (OFF_UH + MAX_IT * NB * P)  // du partials: MAX_IT * IB
#define OFF_BAR  (OFF_DU + MAX_IT * IB)      // 256 uints (8 padded counters)
#define OFF_T    (OFF_BAR + 256)             // T as int
#define OFF_COST (OFF_T + 64)
#define WS_FLOATS (OFF_COST + 64)            // ~37.2 MB

// system-scope publish: visible at the coherence point (crosses XCD L2s)
__device__ __forceinline__ void publish_f(float* p, float v) {
    __hip_atomic_store(p, v, __ATOMIC_RELAXED, __HIP_MEMORY_SCOPE_SYSTEM);
}

// 4x 16B system-scope loads (sc0|sc1: bypass stale L1/L2, read fabric/L3).
// Load + waitcnt in ONE asm block with early-clobber outputs => no use-before-
// complete hazard and no separate-asm hoisting hazard (skill rule #18).
__device__ __forceinline__ void sysld4(float4& w0, float4& w1, float4& w2, float4& w3,
                                       const float* p0, const float* p1,
                                       const float* p2, const float* p3)
{
    asm volatile(
        "global_load_dwordx4 %0, %4, off sc0 sc1\n\t"
        "global_load_dwordx4 %1, %5, off sc0 sc1\n\t"
        "global_load_dwordx4 %2, %6, off sc0 sc1\n\t"
        "global_load_dwordx4 %3, %7, off sc0 sc1\n\t"
        "s_waitcnt vmcnt(0)"
        : "=&v"(w0), "=&v"(w1), "=&v"(w2), "=&v"(w3)
        : "v"(p0), "v"(p1), "v"(p2), "v"(p3)
        : "memory");
}

// ---------------- init ----------------
__global__ __launch_bounds__(256)
void init_k(const float* __restrict__ x, const float* __restrict__ y,
            float* __restrict__ ws)
{
    const int g = blockIdx.x * 256 + threadIdx.x;
    if (g < NB * P) {
        const float4* xr = (const float4*)(x + (size_t)g * D);
        const float4* yr = (const float4*)(y + (size_t)g * D);
        float sx = 0.f, sy = 0.f;
#pragma unroll
        for (int k = 0; k < D / 4; k++) {
            float4 a = xr[k], b = yr[k];
            sx = fmaf(a.x, a.x, fmaf(a.y, a.y, fmaf(a.z, a.z, fmaf(a.w, a.w, sx))));
            sy = fmaf(b.x, b.x, fmaf(b.y, b.y, fmaf(b.z, b.z, fmaf(b.w, b.w, sy))));
        }
        ws[OFF_X2 + g] = sx; ws[OFF_Y2 + g] = sy;
        ws[OFF_U + g] = 0.f; ws[OFF_V + g] = 0.f;
    }
    if (g < 256) ((unsigned*)(ws + OFF_BAR))[g] = 0u;
    if (g < 64)  ws[OFF_COST + g] = 0.f;
}

// ---------------- z and z^T via LDS GEMM, fp16 out ----------------
__global__ __launch_bounds__(256)
void gemm_k(const float* __restrict__ x, const float* __restrict__ y,
            float* __restrict__ ws)
{
    float* x2 = ws + OFF_X2;
    float* y2 = ws + OFF_Y2;
    const int tid   = threadIdx.x;
    const int half_ = blockIdx.x >> 9;
    const int bid   = blockIdx.x & 511;
    const int nB    = bid & 7;
    const int inner = bid >> 3;

    const float* A  = half_ ? y : x;
    const float* B  = half_ ? x : y;
    const float* ra = (half_ ? y2 : x2) + nB * P;
    const float* rb = (half_ ? x2 : y2) + nB * P;
    __half* out = (__half*)(ws + (half_ ? OFF_ZT : OFF_Z)) + (size_t)nB * P * P;

    __shared__ float xs [64 * 68];
    __shared__ float ysT[64 * 64];

    for (int k4 = 0; k4 < 4; k4++) {
        const int t  = inner * 4 + k4;
        const int ti = t >> 4, tj = t & 15;
        const float* abase = A + (size_t)(nB * P + ti * 64) * D;
        const float* bbase = B + (size_t)(nB * P + tj * 64) * D;
#pragma unroll
        for (int k = 0; k < 4; k++) {
            const int f = k * 1024 + tid * 4;
            const int r = f >> 6, c = f & 63;
            float4 a = *(const float4*)(abase + f);
            *(float4*)(xs + r * 68 + c) = a;
            float4 b = *(const float4*)(bbase + f);
            const int pr  = r >> 2;
            const int r3  = r & 3;
            const int t15 = c >> 2;
            ysT[(c + 0) * 64 + (((pr ^ t15) & 15) << 2) + r3] = b.x;
            ysT[(c + 1) * 64 + (((pr ^ t15) & 15) << 2) + r3] = b.y;
            ysT[(c + 2) * 64 + (((pr ^ t15) & 15) << 2) + r3] = b.z;
            ysT[(c + 3) * 64 + (((pr ^ t15) & 15) << 2) + r3] = b.w;
        }
        __syncthreads();
        const int r0 = tid >> 4;
        const int g  = tid & 15;
        const int c0 = g << 2;
#pragma unroll
        for (int rr = 0; rr < 4; rr++) {
            const int row = rr * 16 + r0;
            const float* xrow = xs + row * 68;
            float s0 = 0.f, s1 = 0.f, s2 = 0.f, s3 = 0.f;
#pragma unroll
            for (int d = 0; d < 64; d++) {
                const float xv = xrow[d];
                const float4 yv = *(const float4*)(ysT + d * 64 + ((g ^ ((d >> 2) & 15)) << 2));
                s0 = fmaf(xv, yv.x, s0); s1 = fmaf(xv, yv.y, s1);
                s2 = fmaf(xv, yv.z, s2); s3 = fmaf(xv, yv.w, s3);
            }
            const int gr = ti * 64 + row;
            const int gc = tj * 64 + c0;
            const float xq = ra[gr];
            union { unsigned long long u64; __half h[4]; } p;
            p.h[0] = __float2half_rn(-fmaxf(xq + rb[gc + 0] - 2.f * s0, 0.f) * INV_EPS);
            p.h[1] = __float2half_rn(-fmaxf(xq + rb[gc + 1] - 2.f * s1, 0.f) * INV_EPS);
            p.h[2] = __float2half_rn(-fmaxf(xq + rb[gc + 2] - 2.f * s2, 0.f) * INV_EPS);
            p.h[3] = __float2half_rn(-fmaxf(xq + rb[gc + 3] - 2.f * s3, 0.f) * INV_EPS);
            *(unsigned long long*)(out + (size_t)gr * P + gc) = p.u64;
        }
        __syncthreads();
    }
}

// unpack 8 fp16 + 8 weights -> args
__device__ __forceinline__ void args8(uint4 c, float4 w0, float4 w1, float* zp)
{
    const __half2* h = (const __half2*)&c;
    float2 f;
    f = __half22float2(h[0]); zp[0] = fmaf(w0.x, INV_EPS, f.x); zp[1] = fmaf(w0.y, INV_EPS, f.y);
    f = __half22float2(h[1]); zp[2] = fmaf(w0.z, INV_EPS, f.x); zp[3] = fmaf(w0.w, INV_EPS, f.y);
    f = __half22float2(h[2]); zp[4] = fmaf(w1.x, INV_EPS, f.x); zp[5] = fmaf(w1.y, INV_EPS, f.y);
    f = __half22float2(h[3]); zp[6] = fmaf(w1.z, INV_EPS, f.x); zp[7] = fmaf(w1.w, INV_EPS, f.y);
}

#define MAX4(a,b,c,d) fmaxf(fmaxf(a,b),fmaxf(c,d))

// two interleaved row-LSEs (independent chains overlap)
__device__ __forceinline__ void lse2(uint4 c0a, uint4 c0b, uint4 c1a, uint4 c1b,
                                     float4 w0, float4 w1, float4 w2, float4 w3,
                                     float& o0, float& o1)
{
    float z0[16], z1[16];
    args8(c0a, w0, w1, z0); args8(c0b, w2, w3, z0 + 8);
    args8(c1a, w0, w1, z1); args8(c1b, w2, w3, z1 + 8);

    float m0 = fmaxf(MAX4(z0[0], z0[1], z0[2], z0[3]),  MAX4(z0[4], z0[5], z0[6], z0[7]));
    m0 = fmaxf(m0, fmaxf(MAX4(z0[8], z0[9], z0[10], z0[11]), MAX4(z0[12], z0[13], z0[14], z0[15])));
    float m1 = fmaxf(MAX4(z1[0], z1[1], z1[2], z1[3]),  MAX4(z1[4], z1[5], z1[6], z1[7]));
    m1 = fmaxf(m1, fmaxf(MAX4(z1[8], z1[9], z1[10], z1[11]), MAX4(z1[12], z1[13], z1[14], z1[15])));
#pragma unroll
    for (int off = 32; off; off >>= 1) {
        m0 = fmaxf(m0, __shfl_xor(m0, off, 64));
        m1 = fmaxf(m1, __shfl_xor(m1, off, 64));
    }
    float s0, s1;
    {
        float e0[16], e1[16];
#pragma unroll
        for (int q = 0; q < 16; q++) { e0[q] = __expf(z0[q] - m0); e1[q] = __expf(z1[q] - m1); }
#pragma unroll
        for (int q = 0; q < 8; q++)  { e0[q] += e0[q + 8]; e1[q] += e1[q + 8]; }
#pragma unroll
        for (int q = 0; q < 4; q++)  { e0[q] += e0[q + 4]; e1[q] += e1[q + 4]; }
        s0 = (e0[0] + e0[1]) + (e0[2] + e0[3]);
        s1 = (e1[0] + e1[1]) + (e1[2] + e1[3]);
    }
#pragma unroll
    for (int off = 32; off; off >>= 1) {
        s0 += __shfl_xor(s0, off, 64);
        s1 += __shfl_xor(s1, off, 64);
    }
    o0 = EPS_LOG_MU - EPSF * (m0 + __logf(s0));
    o1 = EPS_LOG_MU - EPSF * (m1 + __logf(s1));
}

// per-batch barrier: plain atomic counter, system-scope poll, no fences
__device__ __forceinline__ void bbar(unsigned* ctr, unsigned target)
{
    __syncthreads();                        // drains each wave's vmcnt before s_barrier
    if (threadIdx.x == 0) {
        __builtin_amdgcn_s_waitcnt(0);
        __hip_atomic_fetch_add(ctr, 1u, __ATOMIC_RELAXED, __HIP_MEMORY_SCOPE_AGENT);
        unsigned g = 0;
        while (__hip_atomic_load(ctr, __ATOMIC_RELAXED, __HIP_MEMORY_SCOPE_SYSTEM) < target) {
            __builtin_amdgcn_s_sleep(2);
            if (++g > (1u << 15)) break;    // degrade (visibly wrong), never hang
        }
    }
    __syncthreads();
}

// ---------------- persistent iteration kernel ----------------
// 512 blocks x 512 threads (2 blocks/CU, 4 waves/SIMD). Each wave owns 2 rows
// of z AND 2 rows of z^T, held in registers for the entire kernel.
__global__ __launch_bounds__(TPB_I, 4)
void iter_k(float* __restrict__ ws)
{
    const __half* z  = (const __half*)(ws + OFF_Z);
    const __half* zT = (const __half*)(ws + OFF_ZT);
    float* uh  = ws + OFF_UH;
    float* v   = ws + OFF_V;
    float* dup = ws + OFF_DU;

    const int tid   = threadIdx.x;
    const int nB    = blockIdx.x & 7;      // XCD pin (perf heuristic only)
    const int inner = blockIdx.x >> 3;     // 0..63
    const int wid   = tid >> 6;            // 0..7
    const int lane  = tid & 63;

    __shared__ float duRed[8];

    const int r0 = inner * 16 + wid * 2;   // this wave's rows: r0, r0+1
    const size_t zbase = (size_t)nB * P * P;

    // z rows resident in registers for all 100 iterations
    const uint4* zr0 = (const uint4*)(z  + zbase + (size_t)(r0    ) * P);
    const uint4* zr1 = (const uint4*)(z  + zbase + (size_t)(r0 + 1) * P);
    const uint4* tr0 = (const uint4*)(zT + zbase + (size_t)(r0    ) * P);
    const uint4* tr1 = (const uint4*)(zT + zbase + (size_t)(r0 + 1) * P);
    const uint4 cz0a = zr0[lane], cz0b = zr0[lane + 64];
    const uint4 cz1a = zr1[lane], cz1b = zr1[lane + 64];
    const uint4 ct0a = tr0[lane], ct0b = tr0[lane + 64];
    const uint4 ct1a = tr1[lane], ct1b = tr1[lane + 64];

    unsigned* ctr = (unsigned*)(ws + OFF_BAR) + nB * 32;   // 128B-padded counter
    const int wo = lane * 8;               // weight float offset (first half)
    float* vb = v + nB * P;

    float uold0 = 0.f, uold1 = 0.f;
    unsigned bstep = 0;

    for (int t = 0; t < MAX_IT; t++) {
        float* ut = uh + (size_t)t * (NB * P) + nB * P;

        // ---- row pass: u_t = f(v_{t-1})   (t=0: v=0)
        float4 w0, w1, w2, w3;
        if (t == 0) {
            w0 = w1 = w2 = w3 = make_float4(0.f, 0.f, 0.f, 0.f);
        } else {
            sysld4(w0, w1, w2, w3, vb + wo, vb + wo + 4, vb + 512 + wo, vb + 512 + wo + 4);
        }
        float un0, un1;
        lse2(cz0a, cz0b, cz1a, cz1b, w0, w1, w2, w3, un0, un1);
        if (lane == 0) {
            publish_f(&ut[r0], un0);
            publish_f(&ut[r0 + 1], un1);
            duRed[wid] = fabsf(un0 - uold0) + fabsf(un1 - uold1);
        }
        uold0 = un0; uold1 = un1;
        __syncthreads();
        if (tid == 0) {
            float d = 0.f;
#pragma unroll
            for (int k = 0; k < 8; k++) d += duRed[k];
            dup[t * IB + blockIdx.x] = d;
        }
        bbar(ctr, BPB * (++bstep));

        // ---- col pass: v_t = g(u_t)
        float4 q0, q1, q2, q3;
        sysld4(q0, q1, q2, q3, ut + wo, ut + wo + 4, ut + 512 + wo, ut + 512 + wo + 4);
        float vn0, vn1;
        lse2(ct0a, ct0b, ct1a, ct1b, q0, q1, q2, q3, vn0, vn1);
        if (lane == 0) {
            publish_f(&vb[r0], vn0);
            publish_f(&vb[r0 + 1], vn1);
        }
        bbar(ctr, BPB * (++bstep));
    }
}

// ---------------- find T, restore u_T ----------------
__global__ __launch_bounds__(1024)
void findT_k(float* __restrict__ ws)
{
    __shared__ float Spart[1024];
    __shared__ float S[MAX_IT];
    __shared__ int Ts;
    const int tid = threadIdx.x;

    {
        const int t = tid >> 3, sub = tid & 7;
        float s = 0.f;
        if (t < MAX_IT) {
            const float* dp = ws + OFF_DU + t * IB + sub * 64;
            for (int i = 0; i < 64; i++) s += dp[i];
        }
        Spart[tid] = s;
    }
    __syncthreads();
    if (tid < MAX_IT) {
        float s = 0.f;
#pragma unroll
        for (int k = 0; k < 8; k++) s += Spart[tid * 8 + k];
        S[tid] = s;
    }
    __syncthreads();
    if (tid == 0) {
        int T = MAX_IT - 1;
        for (int t = 0; t < MAX_IT; t++) if (S[t] < 0.8f) { T = t; break; }
        Ts = T;
        *(int*)(ws + OFF_T) = T;
    }
    __syncthreads();
    const int T = Ts;
    const float* src = ws + OFF_UH + (size_t)T * (NB * P);
    float* u = ws + OFF_U;
    for (int i = tid; i < NB * P; i += 1024) u[i] = src[i];
    if (tid < 64) ws[OFF_COST + tid] = 0.f;
}

// LSE helper for the epilogue kernels (weights via plain pointer)
__device__ __forceinline__ float lse_row(const __half* mat, const float4* wv,
                                         int row, int lane)
{
    const float4* mr = (const float4*)(mat + (size_t)row * P);
    const float4 ca = mr[lane];
    const float4 cb = mr[lane + 64];
    const uint4* cau = (const uint4*)&ca;
    const uint4* cbu = (const uint4*)&cb;
    const float4 wa0 = wv[2 * lane],       wa1 = wv[2 * lane + 1];
    const float4 wb0 = wv[128 + 2 * lane], wb1 = wv[129 + 2 * lane];
    float zv[16];
    args8(*cau, wa0, wa1, zv);
    args8(*cbu, wb0, wb1, zv + 8);
    float m = fmaxf(MAX4(zv[0], zv[1], zv[2], zv[3]), MAX4(zv[4], zv[5], zv[6], zv[7]));
    m = fmaxf(m, fmaxf(MAX4(zv[8], zv[9], zv[10], zv[11]), MAX4(zv[12], zv[13], zv[14], zv[15])));
#pragma unroll
    for (int off = 32; off; off >>= 1) m = fmaxf(m, __shfl_xor(m, off, 64));
    float s = 0.f;
#pragma unroll
    for (int q = 0; q < 16; q++) s += __expf(zv[q] - m);
#pragma unroll
    for (int off = 32; off; off >>= 1) s += __shfl_xor(s, off, 64);
    return EPS_LOG_MU - EPSF * (m + __logf(s));
}

// ---------------- recompute v_T = F(u_T) ----------------
__global__ __launch_bounds__(256)
void colT_k(float* __restrict__ ws)
{
    const __half* zT = (const __half*)(ws + OFF_ZT);
    float* u = ws + OFF_U;
    float* v = ws + OFF_V;
    const int tid   = threadIdx.x;
    const int nB    = blockIdx.x & 7;
    const int inner = blockIdx.x >> 3;
    const int wid   = tid >> 6;
    const int lane  = tid & 63;
    const __half* zTb = zT + (size_t)nB * P * P;
    const float4* ur = (const float4*)(u + nB * P);
#pragma unroll
    for (int rr = 0; rr < 4; rr++) {
        const int col = inner * 16 + wid * 4 + rr;
        const float vn = lse_row(zTb, ur, col, lane);
        if (lane == 0) v[nB * P + col] = vn;
    }
}

// ---------------- final cost ----------------
__global__ __launch_bounds__(256)
void cost_k(float* __restrict__ ws)
{
    const __half* z = (const __half*)(ws + OFF_Z);
    float* u    = ws + OFF_U;
    float* v    = ws + OFF_V;
    float* cost = ws + OFF_COST;
    const int tid   = threadIdx.x;
    const int nB    = blockIdx.x & 7;
    const int inner = blockIdx.x >> 3;
    const int wid   = tid >> 6;
    const int lane  = tid & 63;
    __shared__ float red[4];

    const float4* vr = (const float4*)(v + nB * P);
    float accW = 0.f;
#pragma unroll
    for (int rr = 0; rr < 4; rr++) {
        const int row = inner * 16 + wid * 4 + rr;
        const uint4* mr = (const uint4*)(z + ((size_t)nB * P + row) * P);
        const uint4 ca = mr[lane];
        const uint4 cb = mr[lane + 64];
        const float4 va0 = vr[2 * lane],       va1 = vr[2 * lane + 1];
        const float4 vb0 = vr[128 + 2 * lane], vb1 = vr[129 + 2 * lane];
        float zw[16];
        args8(ca, va0, va1, zw);
        args8(cb, vb0, vb1, zw + 8);
        float zc[16];
        {
            const __half2* ha = (const __half2*)&ca;
            const __half2* hb = (const __half2*)&cb;
            float2 f;
            f = __half22float2(ha[0]); zc[0] = f.x;  zc[1] = f.y;
            f = __half22float2(ha[1]); zc[2] = f.x;  zc[3] = f.y;
            f = __half22float2(ha[2]); zc[4] = f.x;  zc[5] = f.y;
            f = __half22float2(ha[3]); zc[6] = f.x;  zc[7] = f.y;
            f = __half22float2(hb[0]); zc[8] = f.x;  zc[9] = f.y;
            f = __half22float2(hb[1]); zc[10] = f.x; zc[11] = f.y;
            f = __half22float2(hb[2]); zc[12] = f.x; zc[13] = f.y;
            f = __half22float2(hb[3]); zc[14] = f.x; zc[15] = f.y;
        }
        const float ui = u[nB * P + row] * INV_EPS;
#pragma unroll
        for (int q = 0; q < 16; q++)
            accW += __expf(zw[q] + ui) * zc[q];
    }
#pragma unroll
    for (int off = 32; off; off >>= 1) accW += __shfl_xor(accW, off, 64);
    if (lane == 0) red[wid] = accW;
    __syncthreads();
    if (tid == 0)
        atomicAdd(&cost[nB], -EPSF * (red[0] + red[1] + red[2] + red[3]));
}

__global__ void out_k(const float* __restrict__ ws, float* __restrict__ out)
{
    if (threadIdx.x < NB) out[threadIdx.x] = ws[OFF_COST + threadIdx.x];
}

__global__ void sentinel_k(float* __restrict__ out)
{
    if (threadIdx.x < NB) out[threadIdx.x] = 1.0e6f;
}

extern "C" void kernel_launch(void* const* d_in, const int* in_sizes, int n_in,
                              void* d_out, int out_size, void* d_ws, size_t ws_size,
                              hipStream_t stream) {
    const float* x = (const float*)d_in[0];
    const float* y = (const float*)d_in[1];
    float* ws  = (float*)d_ws;
    float* out = (float*)d_out;

    if (ws_size < (size_t)WS_FLOATS * sizeof(float)) {
        sentinel_k<<<1, 64, 0, stream>>>(out);
        return;
    }

    init_k<<<32, 256, 0, stream>>>(x, y, ws);
    gemm_k<<<1024, 256, 0, stream>>>(x, y, ws);
    iter_k<<<IB, TPB_I, 0, stream>>>(ws);
    findT_k<<<1, 1024, 0, stream>>>(ws);
    colT_k<<<512, 256, 0, stream>>>(ws);
    cost_k<<<512, 256, 0, stream>>>(ws);
    out_k<<<1, 64, 0, stream>>>(ws, out);
}